// Round 6
// baseline (294.496 us; speedup 1.0000x reference)
//
#include <hip/hip_runtime.h>
#include <math.h>

// MultiBoxLoss (RetinaNet focal + smooth-L1), MI355X — round 6.
//
// Round-5 evidence: timed iteration is dominated by harness fixed costs
// (785 MB d_ws poison ~115 µs @86% HBM peak, ~207 MB input restore ~65 µs);
// our 4 dispatches are ~50-60 µs total. This round cuts dispatch count 4 -> 2
// and overlaps assignment with the cls_pred stream:
//  - main_kernel: blockIdx.x < NB_NEG -> negsum path (float4 stream of the
//    negative focal term; the long pole, dispatched first); else -> assign
//    path (IoU argmax + smooth-L1 + f64 focal correction for positives).
//    Every block writes its OWN slot in d_ws -> no zero-init -> no memset
//    dispatch, and deterministic finalize summation.
//  - finalize_kernel: 1 wave reduces all slots, applies normalizations.

namespace {

constexpr int C      = 80;
constexpr int MB     = 32;
constexpr int NB_NEG = 256;   // negsum blocks per image

__device__ __forceinline__ float clampp(float p) {
    // jnp.clip(p, 1e-7, 1.0-1e-7); (float)(1.0-1e-7) == ref's weak-typed scalar
    return __builtin_amdgcn_fmed3f(p, 1e-7f, (float)(1.0 - 1e-7));
}

__device__ __forceinline__ float neg_term(float pin) {
    // -0.75 * (1-(1-p))^2 * log(1-p), replicated exactly in the correction.
    const float p  = clampp(pin);
    const float om = __fsub_rn(1.0f, p);
    const float q  = __fsub_rn(1.0f, om);
    return -0.75f * __fmul_rn(__fmul_rn(q, q), __logf(om));
}

// ---------------------------------------------------------------------------
// Fused main kernel. grid ((NB_NEG + nbA), B) x 256.
//   blockIdx.x in [0, NB_NEG)        : negsum stream for image blockIdx.y
//   blockIdx.x in [NB_NEG, NB_NEG+nbA): assignment for 256 anchors
// ---------------------------------------------------------------------------
__global__ __launch_bounds__(256) void main_kernel(
    const float* __restrict__ cls_pred,
    const float* __restrict__ reg_pred,
    const float* __restrict__ annots,
    const float* __restrict__ anchors,
    double* __restrict__ negPart,    // [B][NB_NEG]
    double* __restrict__ corrPart,   // [B][nbA]
    float*  __restrict__ regPart,    // [B][nbA]
    int*    __restrict__ posPart,    // [B][nbA]
    int Na, int nbA)
{
    const int b   = blockIdx.y;
    const int tid = threadIdx.x;

    __shared__ float4 sbox[MB];
    __shared__ float2 smeta[MB];
    __shared__ double swd[4];
    __shared__ float  swf[4];
    __shared__ int    swi[4];

    if (blockIdx.x < NB_NEG) {
        // ================= negsum path (memory-bound float4 stream) ========
        const float4* __restrict__ base =
            reinterpret_cast<const float4*>(cls_pred + (size_t)b * C * (size_t)Na);
        const int n4     = (C * Na) >> 2;      // 4 | C*Na
        const int stride = NB_NEG * 256;

        float a0 = 0.f, a1 = 0.f, a2 = 0.f, a3 = 0.f;
        #pragma unroll 4
        for (int i = blockIdx.x * 256 + tid; i < n4; i += stride) {
            const float4 v = base[i];
            a0 += neg_term(v.x);
            a1 += neg_term(v.y);
            a2 += neg_term(v.z);
            a3 += neg_term(v.w);
        }
        float csum = (a0 + a1) + (a2 + a3);
        #pragma unroll
        for (int off = 32; off > 0; off >>= 1) csum += __shfl_down(csum, off);
        if ((tid & 63) == 0) swf[tid >> 6] = csum;
        __syncthreads();
        if (tid == 0)
            negPart[(size_t)b * NB_NEG + blockIdx.x] =
                (double)((swf[0] + swf[1]) + (swf[2] + swf[3]));
        return;
    }

    // ===================== assignment path =================================
    const int bx  = blockIdx.x - NB_NEG;       // 0..nbA-1
    const int a   = bx * 256 + tid;
    const bool inb = (a < Na);

    if (tid < MB) {
        const float* an = annots + ((size_t)b * MB + tid) * 5;
        float x1 = an[0], y1 = an[1], x2 = an[2], y2 = an[3];
        const float cl = an[4];
        if (cl == -1.0f) { x1 = y1 = x2 = y2 = -1e30f; }  // invalid -> inter==0
        sbox[tid]  = make_float4(x1, y1, x2, y2);
        smeta[tid] = make_float2(__fmul_rn(__fsub_rn(x2, x1), __fsub_rn(y2, y1)), cl);
    }
    __syncthreads();

    float ax1 = 0.f, ay1 = 0.f, ax2 = 0.f, ay2 = 0.f;
    if (inb) {
        const float4 av = *reinterpret_cast<const float4*>(anchors + (size_t)a * 4);
        ax1 = av.x; ay1 = av.y; ax2 = av.z; ay2 = av.w;
    }
    // Exactly-rounded ops everywhere the >=0.5 threshold can see.
    const float a_area = __fmul_rn(__fsub_rn(ax2, ax1), __fsub_rn(ay2, ay1));

    // argmax by exact-ratio ordering via cross-multiplication (uni > 0).
    float ibest = -1.0f, ubest = 1.0f;
    int   jbest = 0;
    #pragma unroll
    for (int j = 0; j < MB; ++j) {
        const float4 bxv = sbox[j];
        const float2 bm  = smeta[j];
        const float iw    = fmaxf(__fsub_rn(fminf(ax2, bxv.z), fmaxf(ax1, bxv.x)), 0.0f);
        const float ih    = fmaxf(__fsub_rn(fminf(ay2, bxv.w), fmaxf(ay1, bxv.y)), 0.0f);
        const float inter = __fmul_rn(iw, ih);
        const float uni   = fmaxf(__fsub_rn(__fadd_rn(a_area, bm.x), inter), 1e-7f);
        if (inter * ubest > ibest * uni) { ibest = inter; ubest = uni; jbest = j; }
    }

    double corr   = 0.0;
    float  my_reg = 0.0f;
    int    my_pos = 0;
    // One exact division: bit-matches the reference's rounded IoU for the
    // selected box at the >=0.5 threshold.
    if (inb && __fdiv_rn(ibest, ubest) >= 0.5f) {
        my_pos = 1;
        const float4 g  = sbox[jbest];
        const int    tc = (int)smeta[jbest].y;

        const float aw  = ax2 - ax1,          ah  = ay2 - ay1;
        const float acx = ax1 + 0.5f * aw,    acy = ay1 + 0.5f * ah;
        const float gwr = g.z - g.x,          ghr = g.w - g.y;
        const float gcx = g.x + 0.5f * gwr,   gcy = g.y + 0.5f * ghr;
        const float gw  = fmaxf(gwr, 1.0f),   gh  = fmaxf(ghr, 1.0f);
        float t[4];
        t[0] = ((gcx - acx) / aw) / 0.1f;
        t[1] = ((gcy - acy) / ah) / 0.1f;
        t[2] = __logf(gw / aw) / 0.2f;
        t[3] = __logf(gh / ah) / 0.2f;
        const size_t rb = ((size_t)b * 4) * (size_t)Na + (size_t)a;
        #pragma unroll
        for (int k = 0; k < 4; ++k) {
            const float d = fabsf(t[k] - reg_pred[rb + (size_t)k * Na]);
            my_reg += (d <= (1.0f / 9.0f)) ? 4.5f * d * d : d - (0.5f / 9.0f);
        }

        // focal correction at (b, tc, a): + pos_term - neg_term.
        const float p  = clampp(cls_pred[((size_t)b * C + tc) * (size_t)Na + (size_t)a]);
        const float om = __fsub_rn(1.0f, p);
        const float pos = 0.25f * __fmul_rn(__fmul_rn(om, om), -__logf(p));
        corr = (double)pos - (double)neg_term(p);
    }

    double rc = corr;
    float  rr = my_reg;
    int    rp = my_pos;
    #pragma unroll
    for (int off = 32; off > 0; off >>= 1) {
        rc += __shfl_down(rc, off);
        rr += __shfl_down(rr, off);
        rp += __shfl_down(rp, off);
    }
    const int w = tid >> 6;
    if ((tid & 63) == 0) { swd[w] = rc; swf[w] = rr; swi[w] = rp; }
    __syncthreads();
    if (tid == 0) {
        double tcorr = 0.0; float treg = 0.f; int tpos = 0;
        #pragma unroll
        for (int i = 0; i < 4; ++i) { tcorr += swd[i]; treg += swf[i]; tpos += swi[i]; }
        const size_t s = (size_t)b * nbA + bx;
        corrPart[s] = tcorr;       // unconditional slot writes: no zero-init,
        regPart[s]  = treg;        // deterministic finalize summation
        posPart[s]  = tpos;
    }
}

// ---------------------------------------------------------------------------
// Finalize: one wave reduces all per-block slots + applies normalizations.
// ---------------------------------------------------------------------------
__global__ void finalize_kernel(const double* __restrict__ negPart,
                                const double* __restrict__ corrPart,
                                const float*  __restrict__ regPart,
                                const int*    __restrict__ posPart,
                                float* __restrict__ out, int B, int nbA)
{
    const int tid = threadIdx.x;   // 64 threads, 1 block
    double tot = 0.0;
    for (int b = 0; b < B; ++b) {
        double cls = 0.0, reg = 0.0;
        int    pos = 0;
        for (int i = tid; i < NB_NEG; i += 64)
            cls += negPart[(size_t)b * NB_NEG + i];
        for (int i = tid; i < nbA; i += 64) {
            cls += corrPart[(size_t)b * nbA + i];
            reg += (double)regPart[(size_t)b * nbA + i];
            pos += posPart[(size_t)b * nbA + i];
        }
        #pragma unroll
        for (int off = 32; off > 0; off >>= 1) {
            cls += __shfl_down(cls, off);
            reg += __shfl_down(reg, off);
            pos += __shfl_down(pos, off);
        }
        if (tid == 0) {
            const double np = (double)pos;
            tot += cls / fmax(np, 1.0);
            if (np > 0.0) tot += reg / (4.0 * np);
        }
    }
    if (tid == 0) out[0] = (float)(tot / (double)B);
}

} // namespace

extern "C" void kernel_launch(void* const* d_in, const int* in_sizes, int n_in,
                              void* d_out, int out_size, void* d_ws, size_t ws_size,
                              hipStream_t stream)
{
    const float* cls_pred = (const float*)d_in[0];
    const float* reg_pred = (const float*)d_in[1];
    const float* annots   = (const float*)d_in[2];
    const float* anchors  = (const float*)d_in[3];
    float* out = (float*)d_out;

    const int Na  = in_sizes[3] / 4;            // 76725
    const int B   = in_sizes[2] / (MB * 5);     // 8
    const int nbA = (Na + 255) / 256;           // 300

    // Slot layout in d_ws (all fully overwritten every launch; no memset).
    double* negPart  = (double*)d_ws;                       // B*NB_NEG doubles
    double* corrPart = negPart + (size_t)B * NB_NEG;        // B*nbA doubles
    float*  regPart  = (float*)(corrPart + (size_t)B * nbA);// B*nbA floats
    int*    posPart  = (int*)(regPart + (size_t)B * nbA);   // B*nbA ints

    dim3 grid(NB_NEG + nbA, B);
    main_kernel<<<grid, 256, 0, stream>>>(cls_pred, reg_pred, annots, anchors,
                                          negPart, corrPart, regPart, posPart,
                                          Na, nbA);
    finalize_kernel<<<1, 64, 0, stream>>>(negPart, corrPart, regPart, posPart,
                                          out, B, nbA);
}